// Round 1
// baseline (261.892 us; speedup 1.0000x reference)
//
#include <hip/hip_runtime.h>

#define NS 10
#define H  100
#define NC 30
#define BETA 3.0f
#define MAX_A 5.0f

__device__ __forceinline__ float tanh_fast(float x) {
    // tanh(x) = 1 - 2/(exp(2x)+1); saturates correctly for large |x|
    float e = __expf(2.0f * x);
    return 1.0f - 2.0f / (e + 1.0f);
}

__global__ __launch_bounds__(256) void net_kernel(
    const float* __restrict__ s, const float* __restrict__ a,
    const float* __restrict__ W1, const float* __restrict__ b1,
    const float* __restrict__ W2, const float* __restrict__ b2,
    const float* __restrict__ L1, const float* __restrict__ bl1,
    const float* __restrict__ WL2, const float* __restrict__ bL2,
    float* __restrict__ out, int Btot)
{
    int b = blockIdx.x * blockDim.x + threadIdx.x;
    if (b >= Btot) return;

    // s row: 10 floats, 40B stride -> 8B aligned; use float2 loads
    float sv[NS];
    const float2* s2 = reinterpret_cast<const float2*>(s + (size_t)b * NS);
    #pragma unroll
    for (int i = 0; i < NS / 2; ++i) {
        float2 t = s2[i];
        sv[2 * i + 0] = t.x;
        sv[2 * i + 1] = t.y;
    }
    float2 av = reinterpret_cast<const float2*>(a)[b];

    float vals[NC], cx[NC], cy[NC];
    #pragma unroll
    for (int n = 0; n < NC; ++n) {
        vals[n] = b2[n];
        cx[n]   = bL2[2 * n + 0];
        cy[n]   = bL2[2 * n + 1];
    }

    for (int k = 0; k < H; ++k) {
        float hv = b1[k];
        float hl = bl1[k];
        #pragma unroll
        for (int i = 0; i < NS; ++i) {
            hv = fmaf(sv[i], W1[i * H + k], hv);
            hl = fmaf(sv[i], L1[i * H + k], hl);
        }
        hv = fmaxf(hv, 0.0f);
        hl = fmaxf(hl, 0.0f);

        #pragma unroll
        for (int n = 0; n < NC; ++n)
            vals[n] = fmaf(hv, W2[k * NC + n], vals[n]);

        #pragma unroll
        for (int n = 0; n < NC; ++n) {
            cx[n] = fmaf(hl, WL2[(n * H + k) * 2 + 0], cx[n]);
            cy[n] = fmaf(hl, WL2[(n * H + k) * 2 + 1], cy[n]);
        }
    }

    float num = 0.0f, den = 0.0f;
    #pragma unroll
    for (int n = 0; n < NC; ++n) {
        float ex = MAX_A * tanh_fast(cx[n]) - av.x;
        float ey = MAX_A * tanh_fast(cy[n]) - av.y;
        float d  = sqrtf(fmaf(ex, ex, ey * ey));
        float w  = __expf(-BETA * d);
        num = fmaf(w, vals[n], num);
        den += w;
    }
    out[b] = num / den;
}

extern "C" void kernel_launch(void* const* d_in, const int* in_sizes, int n_in,
                              void* d_out, int out_size, void* d_ws, size_t ws_size,
                              hipStream_t stream) {
    const float* s   = (const float*)d_in[0];
    const float* a   = (const float*)d_in[1];
    const float* W1  = (const float*)d_in[2];
    const float* b1  = (const float*)d_in[3];
    const float* W2  = (const float*)d_in[4];
    const float* b2  = (const float*)d_in[5];
    const float* L1  = (const float*)d_in[6];
    const float* bl1 = (const float*)d_in[7];
    const float* WL2 = (const float*)d_in[8];
    const float* bL2 = (const float*)d_in[9];
    float* out = (float*)d_out;

    int Btot = out_size;  // [B,1] -> B floats
    int block = 256;
    int grid = (Btot + block - 1) / block;
    net_kernel<<<grid, block, 0, stream>>>(s, a, W1, b1, W2, b2, L1, bl1, WL2, bL2, out, Btot);
}